// Round 3
// baseline (653.969 us; speedup 1.0000x reference)
//
#include <hip/hip_runtime.h>

// cheb_conv_aagcn: B=8,K=3,N=2048,F_IN=16,F_OUT=64,T=12
// out[b,n,o,t] = relu( sum_k (1/Z_k[n]) sum_m exp(S[b,k,m,n]) cheb_k[m,n] x[b,m,:] @ Theta_k )
// cheb0=I (diagonal pick), cheb1=L=diag(deg)-adj, cheb2=2L*L-I (elementwise).
//
// v4: 2-deep load pipeline. Sraw double-buffered; raw s_barrier with explicit
// lgkmcnt(0) (NO vmcnt drain at chunk barriers); PACK gated on counted
// vmcnt(8) so the next chunk's 8 loads stay in flight across the barrier.
// k_deg+k_xt merged into k_prep (concurrent).

#define NB 8
#define NN 2048
#define FT 192
#define BN 32
#define BM 64
#define LBM 72  // Pt row stride in bf16 (144B)
#define ZST 33  // Zred padded stride

typedef __attribute__((ext_vector_type(8))) short short8;
typedef __attribute__((ext_vector_type(4))) float f32x4;

__device__ __forceinline__ unsigned short bf16_rne(float f) {
  unsigned u = __float_as_uint(f);
  u += 0x7FFFu + ((u >> 16) & 1u);
  return (unsigned short)(u >> 16);
}

__device__ __forceinline__ void gload_lds16(const float* g, float* l) {
  __builtin_amdgcn_global_load_lds(
      (const __attribute__((address_space(1))) void*)g,
      (__attribute__((address_space(3))) void*)l, 16, 0, 0);
}

// merged prep: blocks [0,2048): deg row-sums; [2048,2560): xT transpose.
__global__ __launch_bounds__(256) void k_prep(const float* __restrict__ adj,
                                              float* __restrict__ deg,
                                              const float* __restrict__ x,
                                              unsigned short* __restrict__ xT) {
  __shared__ float ls[4];
  const int bid = blockIdx.x;
  if (bid < NN) {
    const float* r = adj + (size_t)bid * NN;
    float s = 0.f;
    for (int j = threadIdx.x; j < NN; j += 256) s += r[j];
    for (int off = 32; off; off >>= 1) s += __shfl_down(s, off, 64);
    if ((threadIdx.x & 63) == 0) ls[threadIdx.x >> 6] = s;
    __syncthreads();
    if (threadIdx.x == 0) deg[bid] = ls[0] + ls[1] + ls[2] + ls[3];
  } else {
    const int xbk = bid - NN;  // 0..511
    const int b = xbk >> 6, m0 = (xbk & 63) * 32;
    const int ft = threadIdx.x;
    if (ft < FT) {
      const float* src = x + (size_t)b * NN * FT + ft;
      uint4* dst = (uint4*)(xT + ((size_t)b * FT + ft) * NN + m0);
#pragma unroll
      for (int g = 0; g < 4; ++g) {
        unsigned u[4];
#pragma unroll
        for (int j = 0; j < 4; ++j) {
          float lo = src[(size_t)(m0 + g * 8 + 2 * j) * FT];
          float hi = src[(size_t)(m0 + g * 8 + 2 * j + 1) * FT];
          u[j] = (unsigned)bf16_rne(lo) | ((unsigned)bf16_rne(hi) << 16);
        }
        dst[g] = make_uint4(u[0], u[1], u[2], u[3]);
      }
    }
  }
}

// grid (64, 8) -> (tile, b) via XCD swizzle, block 256 (4 waves).
__global__ __launch_bounds__(256, 2) void k_fused(
    const float* __restrict__ Sall, const float* __restrict__ adj,
    const float* __restrict__ deg, const unsigned short* __restrict__ xT,
    const float* __restrict__ x, const float* __restrict__ Theta,
    float* __restrict__ out) {
  // flat smem, phase-overlaid:
  //  loop:     SrA1 @0 (8K) | SrA2 @8192 | SrB1 @16384 | SrB2 @24576
  //            Pt[4][32*72 u16] @32768 (18432B) -> 51200
  //  epilogue: Zred[3][32][33] @0 -> r1s[32*196] @0 | r2s @25088 | xs @50176
  __shared__ __align__(16) char smem[74752];
  __shared__ float dEs[BN];
  __shared__ float sc[3][BN];

  float* const SrA1 = (float*)smem;
  float* const SrA2 = (float*)(smem + 8192);
  float* const SrB1 = (float*)(smem + 16384);
  float* const SrB2 = (float*)(smem + 24576);
  unsigned short* const PtB = (unsigned short*)(smem + 32768);

  // XCD swizzle: XCD = flat&7 = b -> xT[b] (786KB) L2-resident per XCD.
  const int flat = blockIdx.x + (blockIdx.y << 6);
  const int b = flat & 7;
  const int tile = flat >> 3;
  const int n0 = tile * BN;

  const int t = threadIdx.x;
  const int lane = t & 63, w = t >> 6;
  const int ln = lane & 15, quad = lane >> 4;
  const int col4 = (t & 7) << 2;  // pack cols
  const int rowg = t >> 3;        // pack row-pair 0..31 (wave w -> rows w*16..+15)
  const int srow = lane >> 3;     // staging row within 8-row gload group
  const int scol = (lane & 7) << 2;

  const float* S0 = Sall + (size_t)b * 3 * NN * NN;
  const float* S1 = S0 + (size_t)NN * NN;
  const float* S2 = S1 + (size_t)NN * NN;
  const unsigned short* xbp = xT + (size_t)b * FT * NN;

  const int cdiag = n0 >> 6;
  const float4 dgv = *(const float4*)(deg + n0 + col4);

  const f32x4 zero4 = {0.f, 0.f, 0.f, 0.f};
  f32x4 acc1[2][3], acc2[2][3];
#pragma unroll
  for (int i = 0; i < 2; ++i)
#pragma unroll
    for (int q = 0; q < 3; ++q) {
      acc1[i][q] = zero4;
      acc2[i][q] = zero4;
    }
  float zp0[4] = {0.f, 0.f, 0.f, 0.f};
  float zp1[4] = {0.f, 0.f, 0.f, 0.f};
  float zp2[4] = {0.f, 0.f, 0.f, 0.f};

  auto STAGE = [&](int c, float* d1, float* d2) {
    const int m0s = c * BM;
#pragma unroll
    for (int j2 = 0; j2 < 2; ++j2) {
      const int r0 = (w << 4) + (j2 << 3);
      const size_t go = (size_t)(m0s + r0 + srow) * NN + n0 + scol;
      gload_lds16(S1 + go, d1 + r0 * BN);
      gload_lds16(S2 + go, d2 + r0 * BN);
    }
  };

  auto LOADAV = [&](int c, float4 av[2], float4 sv[2]) {
#pragma unroll
    for (int r = 0; r < 2; ++r) {
      const int gm = c * BM + rowg * 2 + r;
      av[r] = *(const float4*)(adj + (size_t)gm * NN + n0 + col4);
      sv[r] = *(const float4*)(S0 + (size_t)gm * NN + n0 + col4);
    }
  };

  auto PACK = [&](int c, int pbuf, const float* R1, const float* R2,
                  const float4 av[2], const float4 sv[2]) {
    const bool isd = (c == cdiag);
    unsigned short* P1 = PtB + (size_t)pbuf * 2304;
    unsigned short* P2 = PtB + (size_t)(2 + pbuf) * 2304;
    unsigned short q1[2][4], q2[2][4];
    const float dg[4] = {dgv.x, dgv.y, dgv.z, dgv.w};
#pragma unroll
    for (int r = 0; r < 2; ++r) {
      const int lrow = rowg * 2 + r;
      const float4 s1 = *(const float4*)&R1[lrow * BN + col4];
      const float4 s2 = *(const float4*)&R2[lrow * BN + col4];
      const float se1[4] = {s1.x, s1.y, s1.z, s1.w};
      const float se2[4] = {s2.x, s2.y, s2.z, s2.w};
      const float aa[4] = {av[r].x, av[r].y, av[r].z, av[r].w};
      const float s0e[4] = {sv[r].x, sv[r].y, sv[r].z, sv[r].w};
#pragma unroll
      for (int j = 0; j < 4; ++j) {
        const float e0 = __expf(s0e[j]);
        const float e1 = __expf(se1[j]);
        const float e2 = __expf(se2[j]);
        zp0[j] += e0;
        zp1[j] += e1;
        zp2[j] += e2;
        float c1 = -aa[j];
        float c2 = 2.f * aa[j] * aa[j];
        if (isd) {
          if (c * BM + lrow == n0 + col4 + j) {
            const float L = dg[j] - aa[j];
            c1 = L;
            c2 = 2.f * L * L - 1.f;
            dEs[col4 + j] = e0;
          }
        }
        q1[r][j] = bf16_rne(e1 * c1);
        q2[r][j] = bf16_rne(e2 * c2);
      }
    }
#pragma unroll
    for (int j = 0; j < 4; ++j) {
      const unsigned v1 = (unsigned)q1[0][j] | ((unsigned)q1[1][j] << 16);
      const unsigned v2 = (unsigned)q2[0][j] | ((unsigned)q2[1][j] << 16);
      *(unsigned*)&P1[(col4 + j) * LBM + rowg * 2] = v1;
      *(unsigned*)&P2[(col4 + j) * LBM + rowg * 2] = v2;
    }
  };

  auto BFR = [&](int c, short8 bfr[2][3]) {
    const int m0 = c * BM;
#pragma unroll
    for (int ks2 = 0; ks2 < 2; ++ks2)
#pragma unroll
      for (int q = 0; q < 3; ++q)
        bfr[ks2][q] = *(const short8*)(xbp +
            (size_t)(w * 48 + q * 16 + ln) * NN + m0 + ks2 * 32 + quad * 8);
  };

  auto MFMAh = [&](int pbuf, const short8 bfr[2][3]) {
#pragma unroll
    for (int ks2 = 0; ks2 < 2; ++ks2) {
      short8 a1[2], a2[2];
#pragma unroll
      for (int i = 0; i < 2; ++i) {
        a1[i] = *(const short8*)&PtB[(size_t)pbuf * 2304 + (i * 16 + ln) * LBM +
                                     ks2 * 32 + quad * 8];
        a2[i] = *(const short8*)&PtB[(size_t)(2 + pbuf) * 2304 +
                                     (i * 16 + ln) * LBM + ks2 * 32 + quad * 8];
      }
#pragma unroll
      for (int i = 0; i < 2; ++i)
#pragma unroll
        for (int q = 0; q < 3; ++q) {
          acc1[i][q] = __builtin_amdgcn_mfma_f32_16x16x32_bf16(
              a1[i], bfr[ks2][q], acc1[i][q], 0, 0, 0);
          acc2[i][q] = __builtin_amdgcn_mfma_f32_16x16x32_bf16(
              a2[i], bfr[ks2][q], acc2[i][q], 0, 0, 0);
        }
    }
  };

  float4 avA[2], svA[2], avB[2], svB[2];

  // ---- prologue: stage+pack chunk 0 (A); stage chunk 1 (B) in flight
  STAGE(0, SrA1, SrA2);
  LOADAV(0, avA, svA);
  asm volatile("s_waitcnt vmcnt(0)" ::: "memory");
  __builtin_amdgcn_sched_barrier(0);
  PACK(0, 0, SrA1, SrA2, avA, svA);
  STAGE(1, SrB1, SrB2);
  LOADAV(1, avB, svB);
  asm volatile("s_waitcnt lgkmcnt(0)" ::: "memory");
  __builtin_amdgcn_s_barrier();

  for (int c2 = 0; c2 < 32; c2 += 2) {
    // ---- even half: MFMA chunk c2 (Pt buf0); pack c2+1 from B; stage c2+2->A
    {
      short8 bfr[2][3];
      BFR(c2, bfr);
      __builtin_amdgcn_sched_barrier(0);
      if (c2 + 2 < 32) {
        STAGE(c2 + 2, SrA1, SrA2);
        LOADAV(c2 + 2, avA, svA);
      }
      __builtin_amdgcn_sched_barrier(0);
      MFMAh(0, bfr);
      // wait everything older than chunk c2+2's 8 in-flight loads
      asm volatile("s_waitcnt vmcnt(8)" ::: "memory");
      __builtin_amdgcn_sched_barrier(0);
      PACK(c2 + 1, 1, SrB1, SrB2, avB, svB);
      asm volatile("s_waitcnt lgkmcnt(0)" ::: "memory");
      __builtin_amdgcn_s_barrier();
    }
    // ---- odd half: MFMA chunk c2+1 (Pt buf1); pack c2+2 from A; stage c2+3->B
    {
      short8 bfr[2][3];
      BFR(c2 + 1, bfr);
      __builtin_amdgcn_sched_barrier(0);
      if (c2 + 3 < 32) {
        STAGE(c2 + 3, SrB1, SrB2);
        LOADAV(c2 + 3, avB, svB);
      }
      __builtin_amdgcn_sched_barrier(0);
      MFMAh(1, bfr);
      asm volatile("s_waitcnt vmcnt(8)" ::: "memory");
      __builtin_amdgcn_sched_barrier(0);
      if (c2 + 2 < 32) PACK(c2 + 2, 0, SrA1, SrA2, avA, svA);
      asm volatile("s_waitcnt lgkmcnt(0)" ::: "memory");
      __builtin_amdgcn_s_barrier();
    }
  }

  // ---- Z reductions (overlay Zred onto Sr region; Pt/Sr dead) ----
  float* Zr = (float*)smem;  // [3][32][ZST]
#pragma unroll
  for (int j = 0; j < 4; ++j) {
    Zr[0 * 32 * ZST + rowg * ZST + col4 + j] = zp0[j];
    Zr[1 * 32 * ZST + rowg * ZST + col4 + j] = zp1[j];
    Zr[2 * 32 * ZST + rowg * ZST + col4 + j] = zp2[j];
  }
  __syncthreads();
  if (t < 96) {
    const int which = t >> 5, n = t & 31;
    float Z = 0.f;
#pragma unroll
    for (int g = 0; g < 32; ++g) Z += Zr[which * 32 * ZST + g * ZST + n];
    sc[which][n] = (which == 0) ? (dEs[n] / Z) : (1.f / Z);
  }
  __syncthreads();

  // ---- stage rhs (raw acc) + x rows into LDS ----
  float* const r1s = (float*)smem;            // [32][196]
  float* const r2s = (float*)(smem + 25088);  // [32][196]
  float* const xs = (float*)(smem + 50176);   // [32][192]
#pragma unroll
  for (int i = 0; i < 2; ++i)
#pragma unroll
    for (int q = 0; q < 3; ++q) {
      const int ft = w * 48 + q * 16 + ln;
#pragma unroll
      for (int r = 0; r < 4; ++r) {
        const int nl = i * 16 + quad * 4 + r;
        r1s[nl * 196 + ft] = acc1[i][q][r];
        r2s[nl * 196 + ft] = acc2[i][q][r];
      }
    }
  for (int l = t; l < 32 * 48; l += 256) {
    const int row = l / 48, c4 = (l % 48) * 4;
    *(float4*)&xs[row * 192 + c4] =
        *(const float4*)(x + ((size_t)b * NN + n0 + row) * FT + c4);
  }
  __syncthreads();

  // ---- epilogue: out[n,o,t] = relu(c0*x@Th0 + rz1*rhs1@Th1 + rz2*rhs2@Th2)
  const int o = t & 63, nl2 = t >> 6;
  float th0[16], th1[16], th2[16];
#pragma unroll
  for (int f = 0; f < 16; ++f) {
    th0[f] = Theta[f * 64 + o];
    th1[f] = Theta[(16 + f) * 64 + o];
    th2[f] = Theta[(32 + f) * 64 + o];
  }
#pragma unroll 1
  for (int ni = 0; ni < 8; ++ni) {
    const int n = ni * 4 + nl2;
    float a0[12], a1[12], a2[12];
#pragma unroll
    for (int e = 0; e < 12; ++e) a0[e] = a1[e] = a2[e] = 0.f;
#pragma unroll
    for (int f = 0; f < 16; ++f) {
      const f32x4* xv = (const f32x4*)&xs[n * 192 + f * 12];
      const f32x4* r1v = (const f32x4*)&r1s[n * 196 + f * 12];
      const f32x4* r2v = (const f32x4*)&r2s[n * 196 + f * 12];
#pragma unroll
      for (int g = 0; g < 3; ++g)
#pragma unroll
        for (int e = 0; e < 4; ++e) {
          a0[g * 4 + e] += th0[f] * xv[g][e];
          a1[g * 4 + e] += th1[f] * r1v[g][e];
          a2[g * 4 + e] += th2[f] * r2v[g][e];
        }
    }
    const float c0 = sc[0][n], rz1 = sc[1][n], rz2 = sc[2][n];
    float4* op = (float4*)(out + (((size_t)b * NN + n0 + n) * 64 + o) * 12);
#pragma unroll
    for (int g = 0; g < 3; ++g) {
      float4 rv;
      rv.x = fmaxf(a0[g * 4 + 0] * c0 + a1[g * 4 + 0] * rz1 + a2[g * 4 + 0] * rz2, 0.f);
      rv.y = fmaxf(a0[g * 4 + 1] * c0 + a1[g * 4 + 1] * rz1 + a2[g * 4 + 1] * rz2, 0.f);
      rv.z = fmaxf(a0[g * 4 + 2] * c0 + a1[g * 4 + 2] * rz1 + a2[g * 4 + 2] * rz2, 0.f);
      rv.w = fmaxf(a0[g * 4 + 3] * c0 + a1[g * 4 + 3] * rz1 + a2[g * 4 + 3] * rz2, 0.f);
      op[g] = rv;
    }
  }
}

extern "C" void kernel_launch(void* const* d_in, const int* in_sizes, int n_in,
                              void* d_out, int out_size, void* d_ws,
                              size_t ws_size, hipStream_t stream) {
  (void)in_sizes;
  (void)n_in;
  (void)out_size;
  const float* x = (const float*)d_in[0];
  const float* s_attn = (const float*)d_in[1];
  const float* adj = (const float*)d_in[2];
  const float* Theta = (const float*)d_in[3];
  float* out = (float*)d_out;
  char* ws = (char*)d_ws;

  const size_t szXT = (size_t)NB * FT * NN * 2;  // 6,291,456
  const size_t szDeg = NN * 4;                   // 8,192
  if (ws_size < szXT + szDeg) return;

  unsigned short* xT = (unsigned short*)ws;
  float* deg = (float*)(ws + szXT);

  hipLaunchKernelGGL(k_prep, dim3(NN + 512), dim3(256), 0, stream, adj, deg, x,
                     xT);
  hipLaunchKernelGGL(k_fused, dim3(64, NB), dim3(256), 0, stream, s_attn, adj,
                     deg, xT, x, Theta, out);
}

// Round 4
// 617.008 us; speedup vs baseline: 1.0599x; 1.0599x over previous
//
#include <hip/hip_runtime.h>

// cheb_conv_aagcn: B=8,K=3,N=2048,F_IN=16,F_OUT=64,T=12
// out[b,n,o,t] = relu( sum_k (1/Z_k[n]) sum_m exp(S[b,k,m,n]) cheb_k[m,n] x[b,m,:] @ Theta_k )
// cheb0=I (diagonal pick), cheb1=L=diag(deg)-adj, cheb2=2L*L-I (elementwise).
//
// v5: BN=64 (256B DRAM granule for the 402MB S stream, was 128B), 256 blocks
// of 512 threads (1/CU), fully fused. v4's counted-vmcnt double-buffer
// pipeline kept (load-bearing at 1 block/CU). Epilogue in two 32-row passes.

#define NB 8
#define NN 2048
#define FT 192
#define BN 64
#define BM 64
#define LBM 72  // Pt row stride in bf16 (144B, 16B-aligned)

typedef __attribute__((ext_vector_type(8))) short short8;
typedef __attribute__((ext_vector_type(4))) float f32x4;

__device__ __forceinline__ unsigned short bf16_rne(float f) {
  unsigned u = __float_as_uint(f);
  u += 0x7FFFu + ((u >> 16) & 1u);
  return (unsigned short)(u >> 16);
}

__device__ __forceinline__ void gload_lds16(const float* g, float* l) {
  __builtin_amdgcn_global_load_lds(
      (const __attribute__((address_space(1))) void*)g,
      (__attribute__((address_space(3))) void*)l, 16, 0, 0);
}

// merged prep: blocks [0,2048): deg row-sums; [2048,2560): xT transpose.
__global__ __launch_bounds__(256) void k_prep(const float* __restrict__ adj,
                                              float* __restrict__ deg,
                                              const float* __restrict__ x,
                                              unsigned short* __restrict__ xT) {
  __shared__ float ls[4];
  const int bid = blockIdx.x;
  if (bid < NN) {
    const float* r = adj + (size_t)bid * NN;
    float s = 0.f;
    for (int j = threadIdx.x; j < NN; j += 256) s += r[j];
    for (int off = 32; off; off >>= 1) s += __shfl_down(s, off, 64);
    if ((threadIdx.x & 63) == 0) ls[threadIdx.x >> 6] = s;
    __syncthreads();
    if (threadIdx.x == 0) deg[bid] = ls[0] + ls[1] + ls[2] + ls[3];
  } else {
    const int xbk = bid - NN;  // 0..511
    const int b = xbk >> 6, m0 = (xbk & 63) * 32;
    const int ft = threadIdx.x;
    if (ft < FT) {
      const float* src = x + (size_t)b * NN * FT + ft;
      uint4* dst = (uint4*)(xT + ((size_t)b * FT + ft) * NN + m0);
#pragma unroll
      for (int g = 0; g < 4; ++g) {
        unsigned u[4];
#pragma unroll
        for (int j = 0; j < 4; ++j) {
          float lo = src[(size_t)(m0 + g * 8 + 2 * j) * FT];
          float hi = src[(size_t)(m0 + g * 8 + 2 * j + 1) * FT];
          u[j] = (unsigned)bf16_rne(lo) | ((unsigned)bf16_rne(hi) << 16);
        }
        dst[g] = make_uint4(u[0], u[1], u[2], u[3]);
      }
    }
  }
}

// grid (32, 8) -> (tile, b), block 512 (8 waves), 1 block/CU, XCD = b.
__global__ __launch_bounds__(512, 2) void k_fused(
    const float* __restrict__ Sall, const float* __restrict__ adj,
    const float* __restrict__ deg, const unsigned short* __restrict__ xT,
    const float* __restrict__ x, const float* __restrict__ Theta,
    float* __restrict__ out) {
  // flat smem, phase-overlaid:
  //  loop:     SrA1 @0 (16K) | SrA2 @16384 | SrB1 @32768 | SrB2 @49152
  //            Pt[4][64*72 u16] @65536 (36864B) -> 102400
  //  Zred overlay @0: [3][32][64] f32 (24576B)
  //  epilogue (per 32-row pass): r1s[32*196] @0 | r2s @25088 | xs[32*192] @50176
  __shared__ __align__(16) char smem[102400];
  __shared__ float dEs[BN];
  __shared__ float sc[3][BN];

  float* const SrA1 = (float*)smem;
  float* const SrA2 = (float*)(smem + 16384);
  float* const SrB1 = (float*)(smem + 32768);
  float* const SrB2 = (float*)(smem + 49152);
  unsigned short* const PtB = (unsigned short*)(smem + 65536);

  // XCD swizzle: linear block id round-robins XCDs -> XCD = flat&7 = b.
  const int flat = blockIdx.x + (blockIdx.y << 5);
  const int b = flat & 7;
  const int tile = flat >> 3;
  const int n0 = tile * BN;

  const int t = threadIdx.x;
  const int lane = t & 63, w = t >> 6;  // wave 0..7
  const int wn = w & 1, wf = w >> 1;    // n-half, ft-quarter
  const int ln = lane & 15, quad = lane >> 4;
  const int col4 = (t & 15) << 2;  // pack cols 0..60
  const int rowg = t >> 4;         // pack row-pair 0..31 (wave w -> rows 8w..8w+7)
  const int srow = lane >> 4;      // staging row within 4-row gload group
  const int scol = (lane & 15) << 2;

  const float* S0 = Sall + (size_t)b * 3 * NN * NN;
  const float* S1 = S0 + (size_t)NN * NN;
  const float* S2 = S1 + (size_t)NN * NN;
  const unsigned short* xbp = xT + (size_t)b * FT * NN;

  const int cdiag = tile;  // chunk containing diagonal (BM==BN==64)
  const float4 dgv = *(const float4*)(deg + n0 + col4);

  const f32x4 zero4 = {0.f, 0.f, 0.f, 0.f};
  f32x4 acc1[2][3], acc2[2][3];
#pragma unroll
  for (int i = 0; i < 2; ++i)
#pragma unroll
    for (int q = 0; q < 3; ++q) {
      acc1[i][q] = zero4;
      acc2[i][q] = zero4;
    }
  float zp0[4] = {0.f, 0.f, 0.f, 0.f};
  float zp1[4] = {0.f, 0.f, 0.f, 0.f};
  float zp2[4] = {0.f, 0.f, 0.f, 0.f};

  // wave w stages its own pack rows 8w..8w+7: 2 gloads x 4 rows per matrix.
  auto STAGE = [&](int c, float* d1, float* d2) {
    const int m0s = c * BM;
#pragma unroll
    for (int j2 = 0; j2 < 2; ++j2) {
      const int r0 = (w << 3) + (j2 << 2);
      const size_t go = (size_t)(m0s + r0 + srow) * NN + n0 + scol;
      gload_lds16(S1 + go, d1 + r0 * BN);
      gload_lds16(S2 + go, d2 + r0 * BN);
    }
  };

  auto LOADAV = [&](int c, float4 av[2], float4 sv[2]) {
#pragma unroll
    for (int r = 0; r < 2; ++r) {
      const int gm = c * BM + rowg * 2 + r;
      av[r] = *(const float4*)(adj + (size_t)gm * NN + n0 + col4);
      sv[r] = *(const float4*)(S0 + (size_t)gm * NN + n0 + col4);
    }
  };

  auto PACK = [&](int c, int pbuf, const float* R1, const float* R2,
                  const float4 av[2], const float4 sv[2]) {
    const bool isd = (c == cdiag);
    unsigned short* P1 = PtB + (size_t)pbuf * 4608;
    unsigned short* P2 = PtB + (size_t)(2 + pbuf) * 4608;
    unsigned short q1[2][4], q2[2][4];
    const float dg[4] = {dgv.x, dgv.y, dgv.z, dgv.w};
#pragma unroll
    for (int r = 0; r < 2; ++r) {
      const int lrow = rowg * 2 + r;
      const float4 s1 = *(const float4*)&R1[lrow * BN + col4];
      const float4 s2 = *(const float4*)&R2[lrow * BN + col4];
      const float se1[4] = {s1.x, s1.y, s1.z, s1.w};
      const float se2[4] = {s2.x, s2.y, s2.z, s2.w};
      const float aa[4] = {av[r].x, av[r].y, av[r].z, av[r].w};
      const float s0e[4] = {sv[r].x, sv[r].y, sv[r].z, sv[r].w};
#pragma unroll
      for (int j = 0; j < 4; ++j) {
        const float e0 = __expf(s0e[j]);
        const float e1 = __expf(se1[j]);
        const float e2 = __expf(se2[j]);
        zp0[j] += e0;
        zp1[j] += e1;
        zp2[j] += e2;
        float c1 = -aa[j];
        float c2 = 2.f * aa[j] * aa[j];
        if (isd) {
          if (lrow == col4 + j) {  // global m == global n
            const float L = dg[j] - aa[j];
            c1 = L;
            c2 = 2.f * L * L - 1.f;
            dEs[col4 + j] = e0;
          }
        }
        q1[r][j] = bf16_rne(e1 * c1);
        q2[r][j] = bf16_rne(e2 * c2);
      }
    }
#pragma unroll
    for (int j = 0; j < 4; ++j) {
      const unsigned v1 = (unsigned)q1[0][j] | ((unsigned)q1[1][j] << 16);
      const unsigned v2 = (unsigned)q2[0][j] | ((unsigned)q2[1][j] << 16);
      *(unsigned*)&P1[(col4 + j) * LBM + rowg * 2] = v1;
      *(unsigned*)&P2[(col4 + j) * LBM + rowg * 2] = v2;
    }
  };

  auto BFR = [&](int c, short8 bfr[2][3]) {
    const int m0 = c * BM;
#pragma unroll
    for (int ks2 = 0; ks2 < 2; ++ks2)
#pragma unroll
      for (int q = 0; q < 3; ++q)
        bfr[ks2][q] = *(const short8*)(xbp +
            (size_t)(wf * 48 + q * 16 + ln) * NN + m0 + ks2 * 32 + quad * 8);
  };

  auto MFMAh = [&](int pbuf, const short8 bfr[2][3]) {
#pragma unroll
    for (int ks2 = 0; ks2 < 2; ++ks2) {
      short8 a1[2], a2[2];
#pragma unroll
      for (int i = 0; i < 2; ++i) {
        const int prow = wn * 32 + i * 16 + ln;
        a1[i] = *(const short8*)&PtB[(size_t)pbuf * 4608 + prow * LBM +
                                     ks2 * 32 + quad * 8];
        a2[i] = *(const short8*)&PtB[(size_t)(2 + pbuf) * 4608 + prow * LBM +
                                     ks2 * 32 + quad * 8];
      }
#pragma unroll
      for (int i = 0; i < 2; ++i)
#pragma unroll
        for (int q = 0; q < 3; ++q) {
          acc1[i][q] = __builtin_amdgcn_mfma_f32_16x16x32_bf16(
              a1[i], bfr[ks2][q], acc1[i][q], 0, 0, 0);
          acc2[i][q] = __builtin_amdgcn_mfma_f32_16x16x32_bf16(
              a2[i], bfr[ks2][q], acc2[i][q], 0, 0, 0);
        }
    }
  };

  float4 avA[2], svA[2], avB[2], svB[2];

  // ---- prologue: stage+pack chunk 0 (A); stage chunk 1 (B) in flight
  STAGE(0, SrA1, SrA2);
  LOADAV(0, avA, svA);
  asm volatile("s_waitcnt vmcnt(0)" ::: "memory");
  __builtin_amdgcn_sched_barrier(0);
  PACK(0, 0, SrA1, SrA2, avA, svA);
  STAGE(1, SrB1, SrB2);
  LOADAV(1, avB, svB);
  asm volatile("s_waitcnt lgkmcnt(0)" ::: "memory");
  __builtin_amdgcn_s_barrier();

  for (int c2 = 0; c2 < 32; c2 += 2) {
    // ---- even half: MFMA chunk c2 (buf0); pack c2+1 from B; stage c2+2->A
    {
      short8 bfr[2][3];
      BFR(c2, bfr);
      __builtin_amdgcn_sched_barrier(0);
      if (c2 + 2 < 32) {
        STAGE(c2 + 2, SrA1, SrA2);
        LOADAV(c2 + 2, avA, svA);
      }
      __builtin_amdgcn_sched_barrier(0);
      MFMAh(0, bfr);
      // everything older than chunk c2+2's 8 in-flight loads has landed
      asm volatile("s_waitcnt vmcnt(8)" ::: "memory");
      __builtin_amdgcn_sched_barrier(0);
      PACK(c2 + 1, 1, SrB1, SrB2, avB, svB);
      asm volatile("s_waitcnt lgkmcnt(0)" ::: "memory");
      __builtin_amdgcn_s_barrier();
    }
    // ---- odd half: MFMA chunk c2+1 (buf1); pack c2+2 from A; stage c2+3->B
    {
      short8 bfr[2][3];
      BFR(c2 + 1, bfr);
      __builtin_amdgcn_sched_barrier(0);
      if (c2 + 3 < 32) {
        STAGE(c2 + 3, SrB1, SrB2);
        LOADAV(c2 + 3, avB, svB);
      }
      __builtin_amdgcn_sched_barrier(0);
      MFMAh(1, bfr);
      asm volatile("s_waitcnt vmcnt(8)" ::: "memory");
      __builtin_amdgcn_sched_barrier(0);
      if (c2 + 2 < 32) PACK(c2 + 2, 0, SrA1, SrA2, avA, svA);
      asm volatile("s_waitcnt lgkmcnt(0)" ::: "memory");
      __builtin_amdgcn_s_barrier();
    }
  }

  // ---- Z reductions (overlay Zr onto SrA region; loop LDS dead) ----
  float* Zr = (float*)smem;  // [3][32][64]
#pragma unroll
  for (int j = 0; j < 4; ++j) {
    Zr[(0 * 32 + rowg) * 64 + col4 + j] = zp0[j];
    Zr[(1 * 32 + rowg) * 64 + col4 + j] = zp1[j];
    Zr[(2 * 32 + rowg) * 64 + col4 + j] = zp2[j];
  }
  __syncthreads();
  if (t < 192) {
    const int which = t >> 6, n = t & 63;
    float Z = 0.f;
#pragma unroll
    for (int g = 0; g < 32; ++g) Z += Zr[(which * 32 + g) * 64 + n];
    sc[which][n] = (which == 0) ? (dEs[n] / Z) : (1.f / Z);
  }
  __syncthreads();

  // ---- epilogue: two 32-row passes; out = relu(c0*x@Th0 + rz1*r1@Th1 + rz2*r2@Th2)
  float* const r1s = (float*)smem;            // [32][196]
  float* const r2s = (float*)(smem + 25088);  // [32][196]
  float* const xs = (float*)(smem + 50176);   // [32][192]
  const int o = t & 63, nl8 = t >> 6;         // o, 0..7
  float th0[16], th1[16], th2[16];
#pragma unroll
  for (int f = 0; f < 16; ++f) {
    th0[f] = Theta[f * 64 + o];
    th1[f] = Theta[(16 + f) * 64 + o];
    th2[f] = Theta[(32 + f) * 64 + o];
  }

#pragma unroll 1
  for (int p = 0; p < 2; ++p) {
    if (wn == p) {
#pragma unroll
      for (int i = 0; i < 2; ++i)
#pragma unroll
        for (int q = 0; q < 3; ++q) {
          const int ft = wf * 48 + q * 16 + ln;
#pragma unroll
          for (int r = 0; r < 4; ++r) {
            const int nl = i * 16 + quad * 4 + r;
            r1s[nl * 196 + ft] = acc1[i][q][r];
            r2s[nl * 196 + ft] = acc2[i][q][r];
          }
        }
    }
    for (int l = t; l < 32 * 48; l += 512) {
      const int row = l / 48, c4 = (l % 48) * 4;
      *(float4*)&xs[row * 192 + c4] =
          *(const float4*)(x + ((size_t)b * NN + n0 + p * 32 + row) * FT + c4);
    }
    __syncthreads();
#pragma unroll 1
    for (int ni = 0; ni < 4; ++ni) {
      const int n = ni * 8 + nl8;  // local row in pass
      float a0[12], a1[12], a2[12];
#pragma unroll
      for (int e = 0; e < 12; ++e) a0[e] = a1[e] = a2[e] = 0.f;
#pragma unroll
      for (int f = 0; f < 16; ++f) {
        const f32x4* xv = (const f32x4*)&xs[n * 192 + f * 12];
        const f32x4* r1v = (const f32x4*)&r1s[n * 196 + f * 12];
        const f32x4* r2v = (const f32x4*)&r2s[n * 196 + f * 12];
#pragma unroll
        for (int g = 0; g < 3; ++g)
#pragma unroll
          for (int e = 0; e < 4; ++e) {
            a0[g * 4 + e] += th0[f] * xv[g][e];
            a1[g * 4 + e] += th1[f] * r1v[g][e];
            a2[g * 4 + e] += th2[f] * r2v[g][e];
          }
      }
      const int gn = p * 32 + n;
      const float c0 = sc[0][gn], rz1 = sc[1][gn], rz2 = sc[2][gn];
      float4* op = (float4*)(out + (((size_t)b * NN + n0 + gn) * 64 + o) * 12);
#pragma unroll
      for (int g = 0; g < 3; ++g) {
        float4 rv;
        rv.x = fmaxf(a0[g * 4 + 0] * c0 + a1[g * 4 + 0] * rz1 + a2[g * 4 + 0] * rz2, 0.f);
        rv.y = fmaxf(a0[g * 4 + 1] * c0 + a1[g * 4 + 1] * rz1 + a2[g * 4 + 1] * rz2, 0.f);
        rv.z = fmaxf(a0[g * 4 + 2] * c0 + a1[g * 4 + 2] * rz1 + a2[g * 4 + 2] * rz2, 0.f);
        rv.w = fmaxf(a0[g * 4 + 3] * c0 + a1[g * 4 + 3] * rz1 + a2[g * 4 + 3] * rz2, 0.f);
        op[g] = rv;
      }
    }
    __syncthreads();
  }
}

extern "C" void kernel_launch(void* const* d_in, const int* in_sizes, int n_in,
                              void* d_out, int out_size, void* d_ws,
                              size_t ws_size, hipStream_t stream) {
  (void)in_sizes;
  (void)n_in;
  (void)out_size;
  const float* x = (const float*)d_in[0];
  const float* s_attn = (const float*)d_in[1];
  const float* adj = (const float*)d_in[2];
  const float* Theta = (const float*)d_in[3];
  float* out = (float*)d_out;
  char* ws = (char*)d_ws;

  const size_t szXT = (size_t)NB * FT * NN * 2;  // 6,291,456
  const size_t szDeg = NN * 4;                   // 8,192
  if (ws_size < szXT + szDeg) return;

  unsigned short* xT = (unsigned short*)ws;
  float* deg = (float*)(ws + szXT);

  hipLaunchKernelGGL(k_prep, dim3(NN + 512), dim3(256), 0, stream, adj, deg, x,
                     xT);
  hipLaunchKernelGGL(k_fused, dim3(32, NB), dim3(512), 0, stream, s_attn, adj,
                     deg, xT, x, Theta, out);
}